// Round 1
// baseline (86.989 us; speedup 1.0000x reference)
//
#include <hip/hip_runtime.h>
#include <stdint.h>

typedef __bf16 bf16x8 __attribute__((ext_vector_type(8)));
typedef float f32x4 __attribute__((ext_vector_type(4)));

#define N_ROWS 4096
#define KD 128
#define BM 64
#define NCHUNK 32
#define CHUNK 128                  // whole chunk staged once; ONE barrier per block
#define NBLOCKS (64 * NCHUNK)      // 2048 blocks = 64 I-tiles x 32 chunks; 2 rounds of 4/CU

// Order-preserving float->uint encoding (monotone for all finite floats):
// enc(a) < enc(b)  <=>  a < b. Lets us use atomicMin/Max on unsigned.
#define ENC_POS2 0xC0000000u   // enc(+2.0f)  = "no positive yet" sentinel for min
#define ENC_NEG2 0x3FFFFFFFu   // enc(-2.0f)  = "no negative yet" sentinel for max

__device__ __forceinline__ unsigned enc_f32(float f) {
    union { float f; unsigned u; } v; v.f = f;
    return (v.u & 0x80000000u) ? ~v.u : (v.u | 0x80000000u);
}
__device__ __forceinline__ float dec_f32(unsigned e) {
    union { float f; unsigned u; } v;
    v.u = (e & 0x80000000u) ? (e ^ 0x80000000u) : ~e;
    return v.f;
}

__device__ __forceinline__ unsigned short f32_to_bf16_rne(float f) {
    union { float f; uint32_t u; } v; v.f = f;
    uint32_t u = v.u;
    return (unsigned short)((u + 0x7FFFu + ((u >> 16) & 1u)) >> 16);
}

// XOR-swizzled LDS index for uint4 units: (row, kblock c) -> row*16 + (c ^ (row&15)).
// Coalesced ds_write_b128 and fragment ds_read_b128 both <=2-way per bank group
// (free, m136; validated earlier: killed the 1.1M conflict cycles).
__device__ __forceinline__ int swz(int row, int c) { return row * 16 + (c ^ (row & 15)); }
__device__ __forceinline__ int swzL(int L) { return (L & ~15) | ((L & 15) ^ ((L >> 4) & 15)); }

// One wave per row: L2-normalize, round to bf16 (RNE), pack 2 elems/lane.
// Each block also seeds the hp/hn sentinels for its 4 rows; block 0 zeroes the ticket.
__global__ __launch_bounds__(256) void normalize_kernel(const float* __restrict__ E,
                                                        unsigned short* __restrict__ out,
                                                        unsigned* __restrict__ hp,
                                                        unsigned* __restrict__ hn,
                                                        unsigned* __restrict__ ticket) {
    const int r0 = blockIdx.x * 4;
    if (threadIdx.x < 4) {
        hp[r0 + threadIdx.x] = ENC_POS2;
        hn[r0 + threadIdx.x] = ENC_NEG2;
    }
    if (blockIdx.x == 0 && threadIdx.x == 0) *ticket = 0u;

    const int wave = threadIdx.x >> 6;
    const int lane = threadIdx.x & 63;
    const int row = r0 + wave;
    const float2 v = *(const float2*)&E[row * KD + lane * 2];
    float s = v.x * v.x + v.y * v.y;
#pragma unroll
    for (int m = 1; m < 64; m <<= 1) s += __shfl_xor(s, m, 64);
    float inv = 0.0f;
    if (s > 0.0f) {
        inv = rsqrtf(s);
        inv = inv * (1.5f - 0.5f * s * inv * inv);  // Newton step: ~1e-7 rel err
    }
    const unsigned short a = f32_to_bf16_rne(v.x * inv);
    const unsigned short b = f32_to_bf16_rne(v.y * inv);
    ((uint32_t*)out)[row * (KD / 2) + lane] = ((uint32_t)b << 16) | a;
}

// 2048 blocks = 64 I-tiles x 32 chunks. Whole 128-row B-chunk staged to
// swizzled LDS once (32 KB -> 4 blocks/CU, 2 residency rounds). Per-row
// min/max folded straight into global hp/hn via encoded atomicMin/Max
// (no partials roundtrip); ticket-elected last block computes the loss.
__global__ __launch_bounds__(256) void gram_kernel(const unsigned short* __restrict__ Ebits,
                                                   const int* __restrict__ labels,
                                                   unsigned* __restrict__ hp,
                                                   unsigned* __restrict__ hn,
                                                   unsigned* __restrict__ ticket,
                                                   float* __restrict__ out) {
    __shared__ uint4 Bs4[CHUNK * (KD / 8)];  // 32 KB
    __shared__ int ljs[CHUNK];               // 512 B
    __shared__ unsigned s_old;
    __shared__ float ssum[4];
    __shared__ int scnt[4];

    const int tid = threadIdx.x;
    const int itile = blockIdx.x & 63;
    const int chunk = blockIdx.x >> 6;
    const int ibase = itile * BM;
    const int cbase = chunk * CHUNK;

    const int wave = tid >> 6, lane = tid & 63;
    const int quad = lane >> 4, l15 = lane & 15;
    const int igb = ibase + wave * 16 + quad * 4;  // row base for this lane's accs

    // Stage whole B-chunk: 8 coalesced uint4/thread -> swizzled LDS.
    {
        const uint4* src = (const uint4*)(Ebits + (size_t)cbase * KD);
#pragma unroll
        for (int it = 0; it < 8; ++it) {
            const int L = it * 256 + tid;
            Bs4[swzL(L)] = src[L];
        }
    }
    if (tid < CHUNK) ljs[tid] = labels[cbase + tid];

    // A fragments: one-time global gather, A[m=l15][k = s*32 + quad*8 ..+7].
    bf16x8 afrag[4];
    {
        const uint4* asrc = (const uint4*)Ebits;
        const int arow = ibase + wave * 16 + l15;
#pragma unroll
        for (int s = 0; s < 4; ++s) afrag[s] = *(const bf16x8*)&asrc[arow * 16 + s * 4 + quad];
    }
    int li_lab[4];
#pragma unroll
    for (int r = 0; r < 4; ++r) li_lab[r] = labels[igb + r];

    __syncthreads();  // the only barrier in the main pipeline

    float minpos[4] = {2.0f, 2.0f, 2.0f, 2.0f};   // dots in [-1,1]; 2.0 = "no positive"
    float maxneg[4] = {-2.0f, -2.0f, -2.0f, -2.0f};

    // Pure ds_read + MFMA + epilogue stream: 8 j-tiles, no barriers.
#pragma unroll
    for (int t = 0; t < 8; ++t) {
        f32x4 acc = {0.f, 0.f, 0.f, 0.f};
#pragma unroll
        for (int s = 0; s < 4; ++s) {
            const bf16x8 bfrag = *(const bf16x8*)&Bs4[swz(t * 16 + l15, s * 4 + quad)];
            acc = __builtin_amdgcn_mfma_f32_16x16x32_bf16(afrag[s], bfrag, acc, 0, 0, 0);
        }
        // C/D layout: col = lane&15 (j), row = quad*4 + reg (i)  [m89/m91]
        const int jg = cbase + t * 16 + l15;
        const int lj = ljs[t * 16 + l15];
#pragma unroll
        for (int r = 0; r < 4; ++r) {
            const float d = acc[r];
            const bool same = (lj == li_lab[r]);
            const float dp = (same && (igb + r != jg)) ? d : 2.0f;
            const float dn = same ? -2.0f : d;
            minpos[r] = fminf(minpos[r], dp);
            maxneg[r] = fmaxf(maxneg[r], dn);
        }
    }

    // Reduce across the 16 col-lanes of each quad; rows live in (quad,reg).
#pragma unroll
    for (int m = 1; m < 16; m <<= 1) {
#pragma unroll
        for (int r = 0; r < 4; ++r) {
            minpos[r] = fminf(minpos[r], __shfl_xor(minpos[r], m, 64));
            maxneg[r] = fmaxf(maxneg[r], __shfl_xor(maxneg[r], m, 64));
        }
    }

    // Fold into global per-row accumulators. Sentinel values are no-ops.
    if (l15 == 0) {
#pragma unroll
        for (int r = 0; r < 4; ++r) {
            atomicMin(&hp[igb + r], enc_f32(minpos[r]));
            atomicMax(&hn[igb + r], enc_f32(maxneg[r]));
        }
    }

    // Ticket: __syncthreads drains this block's atomics (vmcnt) before the add
    // (same proven pattern as the old finalize kernel).
    __syncthreads();
    if (tid == 0) s_old = atomicAdd(ticket, 1u);
    __syncthreads();
    if (s_old != (unsigned)(NBLOCKS - 1)) return;

    // ---- Last block: finalize. 256 threads x 16 rows, coalesced. ----
    float sum = 0.f; int cnt = 0;
#pragma unroll
    for (int k = 0; k < 16; ++k) {
        const int row = k * 256 + tid;
        const unsigned ep = __hip_atomic_load(&hp[row], __ATOMIC_RELAXED, __HIP_MEMORY_SCOPE_AGENT);
        const unsigned en = __hip_atomic_load(&hn[row], __ATOMIC_RELAXED, __HIP_MEMORY_SCOPE_AGENT);
        const float mp = dec_f32(ep);   // hardest positive dot (min)
        const float mn = dec_f32(en);   // hardest negative dot (max)
        if (mp < 1.5f && mn > -1.5f) {  // valid: >=1 pos and >=1 neg
            sum += fmaxf(0.f, mn - mp + 0.3f);  // relu(hp_dist - hn_dist + margin)
            ++cnt;
        }
    }
#pragma unroll
    for (int m = 1; m < 64; m <<= 1) {
        sum += __shfl_xor(sum, m, 64);
        cnt += __shfl_xor(cnt, m, 64);
    }
    if (lane == 0) { ssum[wave] = sum; scnt[wave] = cnt; }
    __syncthreads();
    if (tid == 0) {
        const float S = ssum[0] + ssum[1] + ssum[2] + ssum[3];
        const int C = scnt[0] + scnt[1] + scnt[2] + scnt[3];
        out[0] = S / (float)(C > 0 ? C : 1);
    }
}

extern "C" void kernel_launch(void* const* d_in, const int* in_sizes, int n_in,
                              void* d_out, int out_size, void* d_ws, size_t ws_size,
                              hipStream_t stream) {
    const float* E = (const float*)d_in[0];
    const int* labels = (const int*)d_in[1];

    unsigned short* ebits = (unsigned short*)d_ws;                       // 1 MiB
    unsigned* hp = (unsigned*)((char*)d_ws + (size_t)N_ROWS * KD * 2);   // 16 KiB
    unsigned* hn = hp + N_ROWS;                                          // 16 KiB
    unsigned* ticket = hn + N_ROWS;                                      // 4 B
    float* out = (float*)d_out;

    normalize_kernel<<<N_ROWS / 4, 256, 0, stream>>>(E, ebits, hp, hn, ticket);
    gram_kernel<<<NBLOCKS, 256, 0, stream>>>(ebits, labels, hp, hn, ticket, out);
}